// Round 10
// baseline (194.852 us; speedup 1.0000x reference)
//
#include <hip/hip_runtime.h>
#include <hip/hip_bf16.h>
#include <math.h>

#define BB 4
#define CIN 384
#define NHD 6
#define KDIM 16
#define DHEAD 32
#define NPOS 2304
#define DIMS 96
#define DHTOT 192
#define MS 4   // attention m-split

// ---------------- workspace byte offsets (chained; no overlap possible) ----------------
constexpr size_t AL(size_t x) { return (x + 255) & ~(size_t)255; }
constexpr size_t B_SC1 = 0;                                    // 384 f32 (Q part pre-multiplied by log2e)
constexpr size_t B_BS1 = B_SC1 + 384 * 4;
constexpr size_t B_SC2 = B_BS1 + 384 * 4;                      // 96 f32
constexpr size_t B_BS2 = B_SC2 + 96 * 4;
constexpr size_t B_SC3 = B_BS2 + 96 * 4;                       // 384 f32
constexpr size_t B_BS3 = B_SC3 + 384 * 4;
constexpr size_t B_W1  = AL(B_BS3 + 384 * 4);                  // [384 o][384 i] bf16
constexpr size_t B_W2  = AL(B_W1 + (size_t)384 * 384 * 2);     // [96 o][192 i] bf16
constexpr size_t B_W3  = AL(B_W2 + (size_t)96 * 192 * 2);      // [384 o][96 i] bf16
constexpr size_t B_XH  = AL(B_W3 + (size_t)384 * 96 * 2);      // [b][n][i] bf16 hi
constexpr size_t B_XL  = AL(B_XH + (size_t)BB * NPOS * CIN * 2); // [b][n][i] bf16 lo residual
constexpr size_t B_Q   = AL(B_XL + (size_t)BB * NPOS * CIN * 2); // [bh][n][16] bf16 (log2e folded)
constexpr size_t B_K   = AL(B_Q + (size_t)BB * NHD * NPOS * KDIM * 2);  // [bh][m][16] bf16
constexpr size_t B_V   = AL(B_K + (size_t)BB * NHD * NPOS * KDIM * 2);  // [bh][d 32][n] bf16
constexpr size_t B_OP  = AL(B_V + (size_t)BB * NHD * DHEAD * NPOS * 2); // [ms][b][192][n] bf16
constexpr size_t B_LP  = AL(B_OP + (size_t)MS * BB * DHTOT * NPOS * 2); // [ms][bh][n] f32

#define WS_F(off) ((float*)((char*)ws + (off)))
#define WS_U(off) ((ushort*)((char*)ws + (off)))

typedef __attribute__((ext_vector_type(8))) short bf16x8;
typedef __attribute__((ext_vector_type(16))) float f32x16;
typedef __attribute__((ext_vector_type(2))) int int2v;

__device__ inline ushort f2bf(float f) {
    __hip_bfloat16 h = __float2bfloat16(f);
    return *reinterpret_cast<ushort*>(&h);
}
__device__ inline float bf2f(ushort u) {
    uint x = (uint)u << 16;
    return __uint_as_float(x);
}
__device__ inline float exp2_fast(float x) {
    float r;
    asm volatile("v_exp_f32 %0, %1" : "=v"(r) : "v"(x));
    return r;
}
__device__ inline uint cvt_pk_bf16(float lo, float hi) {
    uint r;
    asm volatile("v_cvt_pk_bf16_f32 %0, %1, %2" : "=v"(r) : "v"(lo), "v"(hi));
    return r;
}
// After: a = {a.lo, b.lo}, b = {a.hi, b.hi}  (lane-half exchange)
__device__ inline void phswap(uint& a, uint& b) {
    int2v r = __builtin_amdgcn_permlane32_swap((int)a, (int)b, false, false);
    a = (uint)r[0]; b = (uint)r[1];
}

#define MFMA32(A, B, C) __builtin_amdgcn_mfma_f32_32x32x16_bf16(A, B, C, 0, 0, 0)
#define LOG2E 1.4426950408889634f

// ---------------- setup: weights->bf16, scale/bias, x -> Xh/Xl transpose ----------------
// hi/lo dual conversion via packed v_cvt_pk_bf16_f32: 6 inst per 2 elements
// (vs ~24 for scalar __float2bfloat16 pairs + subs).
__global__ __launch_bounds__(256) void setup_kernel(const float* __restrict__ xx,
                            const float* Wq, const float* qs, const float* qb,
                            const float* Wk, const float* ks, const float* kb,
                            const float* Wv, const float* vs, const float* vb,
                            const float* Wp, const float* ps, const float* pb,
                            const float* Wo, const float* os_, const float* ob,
                            float* ws) {
    // ---- part 1: x tile transpose f32 -> (bf16 hi, bf16 lo) ----
    ushort* Xh = WS_U(B_XH);
    ushort* Xl = WS_U(B_XL);
    int nt = blockIdx.x, it = blockIdx.y, b = blockIdx.z;
    __shared__ float tile[64][68];   // stride 68: rows 16B-aligned for float4
    int t = threadIdx.x;
    int ir = t >> 4, nc = (t & 15) * 4;
    const float* src = xx + ((size_t)b * CIN + it * 64) * NPOS + nt * 64;
#pragma unroll
    for (int ii = 0; ii < 64; ii += 16)
        *(float4*)&tile[ii + ir][nc] = *(const float4*)&src[(size_t)(ii + ir) * NPOS + nc];
    __syncthreads();
    int nl = t >> 2, i16 = (t & 3) * 16;
    uint hw[8], lw[8];
#pragma unroll
    for (int j = 0; j < 8; ++j) {
        float v0 = tile[i16 + 2 * j][nl];
        float v1 = tile[i16 + 2 * j + 1][nl];
        uint h = cvt_pk_bf16(v0, v1);
        float f0 = __uint_as_float(h << 16);
        float f1 = __uint_as_float(h & 0xffff0000u);
        hw[j] = h;
        lw[j] = cvt_pk_bf16(v0 - f0, v1 - f1);
    }
    size_t doff = ((size_t)b * NPOS + nt * 64 + nl) * CIN + it * 64 + i16;
    *(uint4*)(Xh + doff)     = *(uint4*)&hw[0];
    *(uint4*)(Xh + doff + 8) = *(uint4*)&hw[4];
    *(uint4*)(Xl + doff)     = *(uint4*)&lw[0];
    *(uint4*)(Xl + doff + 8) = *(uint4*)&lw[4];

    // ---- part 2: prep (grid-strided across whole launch) ----
    ushort* W1 = WS_U(B_W1);
    ushort* W2 = WS_U(B_W2);
    ushort* W3 = WS_U(B_W3);
    int gid = (blockIdx.z * gridDim.y + blockIdx.y) * gridDim.x + blockIdx.x;
    int idx = gid * 256 + t;
    int stride = gridDim.x * gridDim.y * gridDim.z * 256;
    for (int u = idx; u < 384 * 384; u += stride) {
        int o = u / 384, i = u % 384;
        float v;
        if (o < 96)       v = (i >= 288) ? Wq[o * 96 + (i - 288)] : 0.f;
        else if (o < 192) v = Wk[(o - 96) * 384 + i];
        else              v = Wv[(o - 192) * 384 + i];
        W1[u] = f2bf(v);
    }
    for (int u = idx; u < 96 * 192; u += stride) W2[u] = f2bf(Wp[u]);
    for (int u = idx; u < 384 * 96; u += stride) W3[u] = f2bf(Wo[u]);
    if (idx < 384) {
        float s, bv;
        if (idx < 96)       { s = qs[idx] * LOG2E; bv = qb[idx] * LOG2E; }
        else if (idx < 192) { s = ks[idx - 96];    bv = kb[idx - 96]; }
        else                { s = vs[idx - 192];   bv = vb[idx - 192]; }
        WS_F(B_SC1)[idx] = s;    WS_F(B_BS1)[idx] = bv;
        WS_F(B_SC3)[idx] = os_[idx]; WS_F(B_BS3)[idx] = ob[idx];
    }
    if (idx >= 256 * 256 && idx < 256 * 256 + 96) {
        int j = idx - 256 * 256;
        WS_F(B_SC2)[j] = ps[j]; WS_F(B_BS2)[j] = pb[j];
    }
}

// ---------------- QKV projection: bf16 MFMA (Q/K get hi+lo passes) ----------------
__global__ __launch_bounds__(256) void qkv_mfma(float* ws) {
    const ushort* W1 = WS_U(B_W1);
    const ushort* Xh = WS_U(B_XH);
    const ushort* Xl = WS_U(B_XL);
    const float* sc1 = WS_F(B_SC1);
    const float* bs1 = WS_F(B_BS1);
    ushort* Qb = WS_U(B_Q);
    ushort* Kb = WS_U(B_K);
    ushort* Vt = WS_U(B_V);

    int nt = blockIdx.x, ot = blockIdx.y, b = blockIdx.z;
    int wave = threadIdx.x >> 6, lane = threadIdx.x & 63;
    int l31 = lane & 31, hl = lane >> 5;
    int obase = ot * 64 + (wave >> 1) * 32;
    int nbase = nt * 64 + (wave & 1) * 32;

    const ushort* arow  = W1 + (size_t)(obase + l31) * CIN + hl * 8;
    size_t boff = ((size_t)b * NPOS + nbase + l31) * CIN + hl * 8;
    const ushort* browh = Xh + boff;
    f32x16 acc = {};
#pragma unroll
    for (int k0 = 0; k0 < 384; k0 += 16)
        acc = MFMA32(*(const bf16x8*)(arow + k0), *(const bf16x8*)(browh + k0), acc);
    if (obase < 192) {  // Q/K need the x low-residual pass (exponent-sensitive path)
        const ushort* browl = Xl + boff;
#pragma unroll
        for (int k0 = 0; k0 < 384; k0 += 16)
            acc = MFMA32(*(const bf16x8*)(arow + k0), *(const bf16x8*)(browl + k0), acc);
    }

    int n = nbase + l31;
    if (obase < 192) {
        // packed 8B stores: group g covers o = obase + 8g + 4hl + (0..3), consecutive kk
        ushort* dst = (obase < 96) ? Qb : Kb;
        int ob2 = (obase < 96) ? obase : obase - 96;
#pragma unroll
        for (int g = 0; g < 4; ++g) {
            int od = ob2 + 8 * g + 4 * hl;          // first o of this group (rel)
            ushort4 pk;
            float v0 = acc[4 * g + 0] * sc1[obase + 8 * g + 4 * hl + 0] + bs1[obase + 8 * g + 4 * hl + 0];
            float v1 = acc[4 * g + 1] * sc1[obase + 8 * g + 4 * hl + 1] + bs1[obase + 8 * g + 4 * hl + 1];
            float v2 = acc[4 * g + 2] * sc1[obase + 8 * g + 4 * hl + 2] + bs1[obase + 8 * g + 4 * hl + 2];
            float v3 = acc[4 * g + 3] * sc1[obase + 8 * g + 4 * hl + 3] + bs1[obase + 8 * g + 4 * hl + 3];
            pk.x = f2bf(v0); pk.y = f2bf(v1); pk.z = f2bf(v2); pk.w = f2bf(v3);
            int h = od >> 4, kk = od & 15;
            *(ushort4*)&dst[((size_t)(b * NHD + h) * NPOS + n) * KDIM + kk] = pk;
        }
    } else {
#pragma unroll
        for (int r = 0; r < 16; ++r) {
            int o = obase + (r & 3) + 8 * (r >> 2) + 4 * hl;
            float v = acc[r] * sc1[o] + bs1[o];
            int oo = o - 192;
            int d = oo & 31, hh = oo >> 5;
            Vt[((size_t)(b * NHD + hh) * DHEAD + d) * NPOS + n] = f2bf(v);
        }
    }
}

// ---------------- MFMA flash attention: single-pass, fixed-M (no max), stateless ----
// Scores bounded -> softmax with M=0 is safe in fp32/bf16 exponent range.
// Row-sum l via ones-matrix MFMA (matrix pipe is mostly idle). Partials in bf16.
__global__ __launch_bounds__(256) void attn_mfma(float* ws) {
    const ushort* Qb = WS_U(B_Q);
    const ushort* Kb = WS_U(B_K);
    const ushort* Vt = WS_U(B_V);
    ushort* Opu = WS_U(B_OP);
    float* Lp = WS_F(B_LP);

    int qt = blockIdx.x;   // 18
    int bh = blockIdx.y;   // 24
    int ms = blockIdx.z;   // MS=4
    int wave = threadIdx.x >> 6, lane = threadIdx.x & 63;
    int l31 = lane & 31, hl = lane >> 5;
    int n0 = qt * 128 + wave * 32;
    int n = n0 + l31;

    bf16x8 qf = *(const bf16x8*)(Qb + ((size_t)bh * NPOS + n) * KDIM + hl * 8);
    const ushort* kbase = Kb + (size_t)bh * NPOS * KDIM;
    const ushort* vbase = Vt + (size_t)bh * DHEAD * NPOS + (size_t)l31 * NPOS;

    const short one_bf = (short)0x3F80;   // bf16 1.0
    bf16x8 ones = {one_bf, one_bf, one_bf, one_bf, one_bf, one_bf, one_bf, one_bf};

    f32x16 oacc = (f32x16)0.0f;
    f32x16 lacc = (f32x16)0.0f;

    const int span = NPOS / MS;             // 576
    int mstart = ms * span, mend = mstart + span;
#pragma unroll 2
    for (int m0 = mstart; m0 < mend; m0 += 32) {
        bf16x8 kf = *(const bf16x8*)(kbase + (size_t)(m0 + l31) * KDIM + hl * 8);
        f32x16 s = MFMA32(kf, qf, (f32x16)0.0f);
        // s[r]: q-col = l31, m = m0 + (r&3) + 8*(r>>2) + 4*hl  (log2 domain)
        float p[16];
#pragma unroll
        for (int r = 0; r < 16; ++r) p[r] = exp2_fast(s[r]);

        uint w[8];
#pragma unroll
        for (int j = 0; j < 8; ++j) w[j] = cvt_pk_bf16(p[2 * j], p[2 * j + 1]);
        phswap(w[0], w[2]);
        phswap(w[1], w[3]);
        phswap(w[4], w[6]);
        phswap(w[5], w[7]);

        bf16x8 pb0, pb1;
        ((uint*)&pb0)[0] = w[0]; ((uint*)&pb0)[1] = w[1];
        ((uint*)&pb0)[2] = w[2]; ((uint*)&pb0)[3] = w[3];
        ((uint*)&pb1)[0] = w[4]; ((uint*)&pb1)[1] = w[5];
        ((uint*)&pb1)[2] = w[6]; ((uint*)&pb1)[3] = w[7];

        bf16x8 va0 = *(const bf16x8*)(vbase + m0 + hl * 8);
        bf16x8 va1 = *(const bf16x8*)(vbase + m0 + 16 + hl * 8);
        oacc = MFMA32(va0, pb0, oacc);
        oacc = MFMA32(va1, pb1, oacc);
        lacc = MFMA32(ones, pb0, lacc);   // lacc[r] = sum_m p (all rows equal)
        lacc = MFMA32(ones, pb1, lacc);
    }

    int b = bh / NHD, h = bh % NHD;
    ushort* obp = Opu + ((size_t)(ms * BB + b) * DHTOT + h * DHEAD) * NPOS + n;
#pragma unroll
    for (int r = 0; r < 16; ++r) {
        int d = (r & 3) + 8 * (r >> 2) + 4 * hl;
        obp[(size_t)d * NPOS] = f2bf(oacc[r]);
    }
    if (hl == 0) {
        Lp[(size_t)(ms * 24 + bh) * NPOS + n] = lacc[0];
    }
}

// ---------------- fused tail: combine -> relu -> pproj(+residual) -> oproj -> y -----
__global__ __launch_bounds__(256) void tail_fused(const float* __restrict__ xx,
                                                  float* ws, float* __restrict__ y) {
    const ushort* Opu = WS_U(B_OP);
    const float* Lp = WS_F(B_LP);
    const ushort* W2 = WS_U(B_W2);
    const ushort* W3 = WS_U(B_W3);
    const float* sc2 = WS_F(B_SC2);
    const float* bs2 = WS_F(B_BS2);
    const float* sc3 = WS_F(B_SC3);
    const float* bs3 = WS_F(B_BS3);

    __shared__ ushort obt[32][196];   // [n][ch 192 + pad4]: 2-way bank alias (free)
    __shared__ ushort xrt[32][100];   // [n][o 96 + pad4]:   2-way bank alias (free)

    int nt = blockIdx.x;   // 72 tiles of 32 n
    int b  = blockIdx.y;   // 4
    int n0 = nt * 32;
    int t = threadIdx.x;
    int wave = t >> 6, lane = t & 63;
    int l31 = lane & 31, hl = lane >> 5;

    // ---- step A: combine MS partials (shared fixed M -> plain sums), relu -> obt ----
    {
        int nn = t & 31, cgrp = t >> 5;   // cgrp 0..7
        int n = n0 + nn;
        for (int h = 0; h < NHD; ++h) {
            int bh = b * NHD + h;
            float denom = 0.f;
#pragma unroll
            for (int s = 0; s < MS; ++s) denom += Lp[(size_t)(s * 24 + bh) * NPOS + n];
            float inv = 1.f / denom;
#pragma unroll
            for (int j = 0; j < 4; ++j) {
                int c = h * 32 + cgrp + 8 * j;    // channel
                float v = 0.f;
#pragma unroll
                for (int s = 0; s < MS; ++s)
                    v += bf2f(Opu[((size_t)(s * BB + b) * DHTOT + c) * NPOS + n]);
                obt[nn][c] = f2bf(fmaxf(v * inv, 0.f));
            }
        }
    }
    __syncthreads();

    // ---- step B: pproj (out 96 x n32) + residual -> xrt LDS ----
    if (wave < 3) {
        int o0 = wave * 32;
        const ushort* arow = W2 + (size_t)(o0 + l31) * DHTOT + hl * 8;
        f32x16 acc = {};
#pragma unroll
        for (int k0 = 0; k0 < 192; k0 += 16)
            acc = MFMA32(*(const bf16x8*)(arow + k0), *(const bf16x8*)&obt[l31][k0 + hl * 8], acc);
        int n = n0 + l31;
#pragma unroll
        for (int r = 0; r < 16; ++r) {
            int o = o0 + (r & 3) + 8 * (r >> 2) + 4 * hl;
            float v = acc[r] * sc2[o] + bs2[o] + xx[((size_t)b * CIN + 288 + o) * NPOS + n];
            xrt[l31][o] = f2bf(v);
        }
    }
    __syncthreads();

    // ---- step C: oproj (out 384 x n32) -> y ----
#pragma unroll
    for (int j = 0; j < 3; ++j) {
        int o0 = (wave * 3 + j) * 32;
        const ushort* arow = W3 + (size_t)(o0 + l31) * DIMS + hl * 8;
        f32x16 acc = {};
#pragma unroll
        for (int k0 = 0; k0 < 96; k0 += 16)
            acc = MFMA32(*(const bf16x8*)(arow + k0), *(const bf16x8*)&xrt[l31][k0 + hl * 8], acc);
        int n = n0 + l31;
#pragma unroll
        for (int r = 0; r < 16; ++r) {
            int o = o0 + (r & 3) + 8 * (r >> 2) + 4 * hl;
            y[((size_t)b * CIN + o) * NPOS + n] = fmaxf(acc[r] * sc3[o] + bs3[o], 0.f);
        }
    }
}

extern "C" void kernel_launch(void* const* d_in, const int* in_sizes, int n_in,
                              void* d_out, int out_size, void* d_ws, size_t ws_size,
                              hipStream_t stream) {
    const float* xx = (const float*)d_in[0];
    const float* Wq = (const float*)d_in[1];
    const float* qs = (const float*)d_in[2];
    const float* qb = (const float*)d_in[3];
    const float* Wk = (const float*)d_in[4];
    const float* ks = (const float*)d_in[5];
    const float* kb = (const float*)d_in[6];
    const float* Wv = (const float*)d_in[7];
    const float* vs = (const float*)d_in[8];
    const float* vb = (const float*)d_in[9];
    const float* Wp = (const float*)d_in[10];
    const float* ps = (const float*)d_in[11];
    const float* pb = (const float*)d_in[12];
    const float* Wo = (const float*)d_in[13];
    const float* os_ = (const float*)d_in[14];
    const float* ob = (const float*)d_in[15];
    float* ws = (float*)d_ws;
    float* y = (float*)d_out;

    setup_kernel<<<dim3(36, 6, BB), 256, 0, stream>>>(xx, Wq, qs, qb, Wk, ks, kb,
                                                      Wv, vs, vb, Wp, ps, pb,
                                                      Wo, os_, ob, ws);
    qkv_mfma<<<dim3(36, 6, BB), 256, 0, stream>>>(ws);
    attn_mfma<<<dim3(18, 24, MS), 256, 0, stream>>>(ws);
    tail_fused<<<dim3(72, BB), 256, 0, stream>>>(xx, ws, y);
}